// Round 14
// baseline (54.516 us; speedup 1.0000x reference)
//
#include <hip/hip_runtime.h>
#include <math.h>

typedef float v4 __attribute__((ext_vector_type(4)));
typedef float v2 __attribute__((ext_vector_type(2)));

// Full stable softplus [2 trans]
__device__ __forceinline__ float spf(float x) {
    float a = fabsf(x);
    float e = __expf(-a);
    float l = __logf(1.0f + e);
    return fmaxf(x, 0.0f) + l;
}
// Naive softplus [2 trans], safe for x in (-87, 88)
__device__ __forceinline__ float spn(float x) {
    return __logf(1.0f + __expf(x));
}
__device__ __forceinline__ float sigm(float x) {
    return 1.0f / (1.0f + __expf(-x));
}
__device__ __forceinline__ v4 splat(float s) { v4 r; r.x=s; r.y=s; r.z=s; r.w=s; return r; }
__device__ __forceinline__ v4 sp4(v4 x) {
    v4 r; r.x=spf(x.x); r.y=spf(x.y); r.z=spf(x.z); r.w=spf(x.w); return r;
}
__device__ __forceinline__ v4 sp4n(v4 x) {
    v4 r; r.x=spn(x.x); r.y=spn(x.y); r.z=spn(x.z); r.w=spn(x.w); return r;
}
// Quick softplus for z > 2: z + e^-z, |err| <= 0.0084 [1 trans]
__device__ __forceinline__ v4 spq4(v4 x) {
    v4 r;
    r.x = x.x + __expf(-x.x);
    r.y = x.y + __expf(-x.y);
    r.z = x.z + __expf(-x.z);
    r.w = x.w + __expf(-x.w);
    return r;
}
__device__ __forceinline__ v4 vfma(v4 a, float b, v4 c) {
    v2 bb; bb.x = b; bb.y = b;
    v4 r;
    r.lo = __builtin_elementwise_fma(a.lo, bb, c.lo);
    r.hi = __builtin_elementwise_fma(a.hi, bb, c.hi);
    return r;
}
__device__ __forceinline__ v4 vmin(v4 a, v4 b) {
    v4 r; r.x=fminf(a.x,b.x); r.y=fminf(a.y,b.y); r.z=fminf(a.z,b.z); r.w=fminf(a.w,b.w); return r;
}

// Setup: e_id, h_s, folded epilogue consts. H = h_s*I exactly (see R0 analysis).
__global__ void setup_kernel(const float* __restrict__ W0, const float* __restrict__ b0,
                             const float* __restrict__ Wh, const float* __restrict__ bh,
                             const float* __restrict__ Wf, const float* __restrict__ bf,
                             float* __restrict__ ws) {
    if (threadIdx.x != 0 || blockIdx.x != 0) return;
    float x[4] = {3.f, 1.f, -1.f, 3.f};
    float zin[5], h[5], zh[4][5];
    for (int j = 0; j < 5; ++j) {
        float z = b0[j];
        for (int m = 0; m < 4; ++m) z += x[m] * W0[m * 5 + j];
        zin[j] = z; h[j] = spf(z);
    }
    for (int i = 0; i < 4; ++i) {
        float hn[5];
        for (int j = 0; j < 5; ++j) {
            float z = bh[i * 5 + j];
            for (int k = 0; k < 5; ++k) z += h[k] * Wh[i * 25 + k * 5 + j];
            zh[i][j] = z; hn[j] = spf(z);
        }
        for (int j = 0; j < 5; ++j) h[j] = hn[j];
    }
    float zf = bf[0];
    for (int k = 0; k < 5; ++k) zf += h[k] * Wf[k];
    float e_id = spf(zf);
    float d[5];
    float szf = sigm(zf);
    for (int k = 0; k < 5; ++k) d[k] = Wf[k] * szf;
    for (int i = 3; i >= 0; --i) {
        float dz[5];
        for (int j = 0; j < 5; ++j) dz[j] = d[j] * sigm(zh[i][j]);
        for (int k = 0; k < 5; ++k) {
            float acc = 0.f;
            for (int j = 0; j < 5; ++j) acc += Wh[i * 25 + k * 5 + j] * dz[j];
            d[k] = acc;
        }
    }
    float dz0[5], g[4];
    for (int j = 0; j < 5; ++j) dz0[j] = d[j] * sigm(zin[j]);
    for (int m = 0; m < 4; ++m) {
        float acc = 0.f;
        for (int j = 0; j < 5; ++j) acc += W0[m * 5 + j] * dz0[j];
        g[m] = acc;
    }
    float h_s = -(2.f * g[0] + g[1] - g[2] + 4.f * g[3]);
    float c1 = 0.5f * h_s;
    ws[0] = e_id;
    ws[1] = h_s;
    ws[2] = c1;                    // res = e + c0 + c1*trC
    ws[3] = -e_id - 3.0f * c1;     // c0
}

__device__ __forceinline__ float scalar_sample(const float* f,
        const float* W0, const float* b0, const float* Wh, const float* bh,
        const float* Wf, const float* bf, float e_id, float h_s) {
    float f0=f[0],f1=f[1],f2=f[2],f3=f[3],f4=f[4],f5=f[5],f6=f[6],f7=f[7],f8=f[8];
    float c00=f0*f0+f3*f3+f6*f6, c11=f1*f1+f4*f4+f7*f7, c22=f2*f2+f5*f5+f8*f8;
    float c01=f0*f1+f3*f4+f6*f7, c02=f0*f2+f3*f5+f6*f8, c12=f1*f2+f4*f5+f7*f8;
    float trC=c00+c11+c22;
    float trC2=c00*c00+c11*c11+c22*c22+2.f*(c01*c01+c02*c02+c12*c12);
    float I2=0.5f*(trC*trC-trC2);
    float J=f0*(f4*f8-f5*f7)-f1*(f3*f8-f5*f6)+f2*(f3*f7-f4*f6);
    float h[5];
    for (int j=0;j<5;++j)
        h[j]=spf(b0[j]+trC*W0[j]+J*(W0[5+j]-W0[10+j])+I2*W0[15+j]);
    for (int l=0;l<4;++l){
        float hn[5];
        for (int j=0;j<5;++j){
            float z=bh[l*5+j];
            for (int k=0;k<5;++k) z=fmaf(h[k],Wh[l*25+k*5+j],z);
            hn[j]=spf(z);
        }
        for (int j=0;j<5;++j) h[j]=hn[j];
    }
    float zf=bf[0];
    for (int k=0;k<5;++k) zf=fmaf(h[k],Wf[k],zf);
    return (spf(zf)-e_id)+h_s*0.5f*(trC-3.0f);
}

// Invariants; I2 via principal 2x2 minors.
__device__ __forceinline__ void inv9(
        float f0, float f1, float f2, float f3, float f4,
        float f5, float f6, float f7, float f8,
        float& tc_o, float& J_o, float& I2_o) {
    float c00=f0*f0+f3*f3+f6*f6, c11=f1*f1+f4*f4+f7*f7, c22=f2*f2+f5*f5+f8*f8;
    float c01=f0*f1+f3*f4+f6*f7, c02=f0*f2+f3*f5+f6*f8, c12=f1*f2+f4*f5+f7*f8;
    tc_o = c00+c11+c22;
    float m0 = fmaf(c00, c11, -(c01*c01));
    float m1 = fmaf(c00, c22, -(c02*c02));
    float m2 = fmaf(c11, c22, -(c12*c12));
    I2_o = m0 + m1 + m2;
    float t0 = fmaf(f4, f8, -(f5*f7));
    float t1 = fmaf(f3, f8, -(f5*f6));
    float t2 = fmaf(f3, f7, -(f4*f6));
    J_o = fmaf(f2, t2, fmaf(-f1, t1, f0*t0));
}

// 8 samples/thread as two interleaved v4 groups (A,B): all 18 loads upfront,
// one wave-vote per layer covering both groups, dual independent chains.
__global__ __launch_bounds__(256) void main_kernel(
        const float* __restrict__ F,
        const float* __restrict__ W0, const float* __restrict__ b0,
        const float* __restrict__ Wh, const float* __restrict__ bh,
        const float* __restrict__ Wf, const float* __restrict__ bf,
        const float* __restrict__ cs,   // [e_id, h_s, c1, c0]
        float* __restrict__ out, int n) {
    const long long t = (long long)blockIdx.x * blockDim.x + threadIdx.x;
    const long long i0 = t * 8;
    if (i0 >= n) return;

    if (i0 + 8 <= (long long)n) {
        const v4* p = (const v4*)(F + i0 * 9);
        v4 a0=p[0], a1=p[1], a2=p[2], a3=p[3], a4=p[4], a5=p[5], a6=p[6], a7=p[7], a8=p[8];
        v4 b0v=p[9], b1=p[10], b2=p[11], b3=p[12], b4=p[13], b5=p[14], b6=p[15], b7=p[16], b8=p[17];

        float w0,w1,w2, x0,x1,x2, y0,y1,y2, u0,u1,u2;
        inv9(a0.x,a0.y,a0.z,a0.w, a1.x,a1.y,a1.z,a1.w, a2.x, w0,x0,y0);
        inv9(a2.y,a2.z,a2.w, a3.x,a3.y,a3.z,a3.w, a4.x,a4.y, w1,x1,y1);
        inv9(a4.z,a4.w, a5.x,a5.y,a5.z,a5.w, a6.x,a6.y,a6.z, w2,x2,y2);
        inv9(a6.w, a7.x,a7.y,a7.z,a7.w, a8.x,a8.y,a8.z,a8.w, u0,u1,u2);
        v4 trCA, JA, I2A;
        trCA.x=w0; trCA.y=w1; trCA.z=w2; trCA.w=u0;
        JA.x=x0; JA.y=x1; JA.z=x2; JA.w=u1;
        I2A.x=y0; I2A.y=y1; I2A.z=y2; I2A.w=u2;
        inv9(b0v.x,b0v.y,b0v.z,b0v.w, b1.x,b1.y,b1.z,b1.w, b2.x, w0,x0,y0);
        inv9(b2.y,b2.z,b2.w, b3.x,b3.y,b3.z,b3.w, b4.x,b4.y, w1,x1,y1);
        inv9(b4.z,b4.w, b5.x,b5.y,b5.z,b5.w, b6.x,b6.y,b6.z, w2,x2,y2);
        inv9(b6.w, b7.x,b7.y,b7.z,b7.w, b8.x,b8.y,b8.z,b8.w, u0,u1,u2);
        v4 trCB, JB, I2B;
        trCB.x=w0; trCB.y=w1; trCB.z=w2; trCB.w=u0;
        JB.x=x0; JB.y=x1; JB.z=x2; JB.w=u1;
        I2B.x=y0; I2B.y=y1; I2B.z=y2; I2B.w=u2;

        v4 hA0,hA1,hA2,hA3,hA4, hB0,hB1,hB2,hB3,hB4;
        {
            v4 zA0,zA1,zA2,zA3,zA4, zB0,zB1,zB2,zB3,zB4;
            #define L0Z(J_, ZA_, ZB_) \
                { float wj0=W0[J_], wj1=W0[5+J_]-W0[10+J_], wj3=W0[15+J_], bj=b0[J_]; \
                  ZA_ = splat(bj); \
                  ZA_ = vfma(trCA, wj0, ZA_); ZA_ = vfma(JA, wj1, ZA_); ZA_ = vfma(I2A, wj3, ZA_); \
                  ZB_ = splat(bj); \
                  ZB_ = vfma(trCB, wj0, ZB_); ZB_ = vfma(JB, wj1, ZB_); ZB_ = vfma(I2B, wj3, ZB_); }
            L0Z(0,zA0,zB0) L0Z(1,zA1,zB1) L0Z(2,zA2,zB2) L0Z(3,zA3,zB3) L0Z(4,zA4,zB4)
            #undef L0Z
            v4 m = vmin(vmin(vmin(zA0,zA1),vmin(zA2,zA3)),zA4);
            m = vmin(m, vmin(vmin(vmin(zB0,zB1),vmin(zB2,zB3)),zB4));
            float mm = fminf(fminf(m.x,m.y),fminf(m.z,m.w));
            if (__all(mm > 3.0f)) {
                hA0=spq4(zA0); hA1=spq4(zA1); hA2=spq4(zA2); hA3=spq4(zA3); hA4=spq4(zA4);
                hB0=spq4(zB0); hB1=spq4(zB1); hB2=spq4(zB2); hB3=spq4(zB3); hB4=spq4(zB4);
            } else {
                hA0=sp4n(zA0); hA1=sp4n(zA1); hA2=sp4n(zA2); hA3=sp4n(zA3); hA4=sp4n(zA4);
                hB0=sp4n(zB0); hB1=sp4n(zB1); hB2=sp4n(zB2); hB3=sp4n(zB3); hB4=sp4n(zB4);
            }
        }
        #pragma unroll
        for (int l = 0; l < 4; ++l) {
            v4 zA0,zA1,zA2,zA3,zA4, zB0,zB1,zB2,zB3,zB4;
            #define ZJ(J_, ZA_, ZB_) \
                { float q0=Wh[l*25+0*5+J_], q1=Wh[l*25+1*5+J_], q2=Wh[l*25+2*5+J_], \
                        q3=Wh[l*25+3*5+J_], q4=Wh[l*25+4*5+J_], bj=bh[l*5+J_]; \
                  ZA_ = splat(bj); \
                  ZA_ = vfma(hA0,q0,ZA_); ZA_ = vfma(hA1,q1,ZA_); ZA_ = vfma(hA2,q2,ZA_); \
                  ZA_ = vfma(hA3,q3,ZA_); ZA_ = vfma(hA4,q4,ZA_); \
                  ZB_ = splat(bj); \
                  ZB_ = vfma(hB0,q0,ZB_); ZB_ = vfma(hB1,q1,ZB_); ZB_ = vfma(hB2,q2,ZB_); \
                  ZB_ = vfma(hB3,q3,ZB_); ZB_ = vfma(hB4,q4,ZB_); }
            ZJ(0,zA0,zB0) ZJ(1,zA1,zB1) ZJ(2,zA2,zB2) ZJ(3,zA3,zB3) ZJ(4,zA4,zB4)
            #undef ZJ
            v4 m = vmin(vmin(vmin(zA0,zA1),vmin(zA2,zA3)),zA4);
            m = vmin(m, vmin(vmin(vmin(zB0,zB1),vmin(zB2,zB3)),zB4));
            float mm = fminf(fminf(m.x,m.y),fminf(m.z,m.w));
            if (__all(mm > 17.0f)) {
                hA0=zA0; hA1=zA1; hA2=zA2; hA3=zA3; hA4=zA4;
                hB0=zB0; hB1=zB1; hB2=zB2; hB3=zB3; hB4=zB4;
            } else if (__all(mm > 2.0f)) {
                hA0=spq4(zA0); hA1=spq4(zA1); hA2=spq4(zA2); hA3=spq4(zA3); hA4=spq4(zA4);
                hB0=spq4(zB0); hB1=spq4(zB1); hB2=spq4(zB2); hB3=spq4(zB3); hB4=spq4(zB4);
            } else {
                hA0=sp4(zA0); hA1=sp4(zA1); hA2=sp4(zA2); hA3=sp4(zA3); hA4=sp4(zA4);
                hB0=sp4(zB0); hB1=sp4(zB1); hB2=sp4(zB2); hB3=sp4(zB3); hB4=sp4(zB4);
            }
        }
        v4 zfA = splat(bf[0]), zfB = splat(bf[0]);
        zfA = vfma(hA0, Wf[0], zfA); zfB = vfma(hB0, Wf[0], zfB);
        zfA = vfma(hA1, Wf[1], zfA); zfB = vfma(hB1, Wf[1], zfB);
        zfA = vfma(hA2, Wf[2], zfA); zfB = vfma(hB2, Wf[2], zfB);
        zfA = vfma(hA3, Wf[3], zfA); zfB = vfma(hB3, Wf[3], zfB);
        zfA = vfma(hA4, Wf[4], zfA); zfB = vfma(hB4, Wf[4], zfB);
        v4 m = vmin(zfA, zfB);
        float mf = fminf(fminf(m.x,m.y),fminf(m.z,m.w));
        v4 eA, eB;
        if (__all(mf > 17.0f)) { eA = zfA; eB = zfB; }
        else if (__all(mf > 2.0f)) { eA = spq4(zfA); eB = spq4(zfB); }
        else { eA = sp4(zfA); eB = sp4(zfB); }

        const float c1 = cs[2], c0 = cs[3];
        v4 resA = vfma(trCA, c1, eA + splat(c0));
        v4 resB = vfma(trCB, c1, eB + splat(c0));
        v4* o = (v4*)(out + i0);
        o[0] = resA;
        o[1] = resB;
    } else {
        const float eid = cs[0], hs = cs[1];
        for (int s = 0; s < (int)(n - i0); ++s)
            out[i0 + s] = scalar_sample(F + (size_t)(i0 + s) * 9, W0, b0, Wh, bh, Wf, bf, eid, hs);
    }
}

extern "C" void kernel_launch(void* const* d_in, const int* in_sizes, int n_in,
                              void* d_out, int out_size, void* d_ws, size_t ws_size,
                              hipStream_t stream) {
    const float* F  = (const float*)d_in[0];
    const float* W0 = (const float*)d_in[1];
    const float* b0 = (const float*)d_in[2];
    const float* Wh = (const float*)d_in[3];
    const float* bh = (const float*)d_in[4];
    const float* Wf = (const float*)d_in[5];
    const float* bf = (const float*)d_in[6];
    float* out = (float*)d_out;
    float* ws  = (float*)d_ws;
    int n = in_sizes[0] / 9;
    setup_kernel<<<1, 64, 0, stream>>>(W0, b0, Wh, bh, Wf, bf, ws);
    int block = 256;
    long long threads = ((long long)n + 7) / 8;
    int grid = (int)((threads + block - 1) / block);
    if (grid < 1) grid = 1;
    main_kernel<<<grid, block, 0, stream>>>(F, W0, b0, Wh, bh, Wf, bf, ws, out, n);
}

// Round 15
// 51.698 us; speedup vs baseline: 1.0545x; 1.0545x over previous
//
#include <hip/hip_runtime.h>
#include <math.h>

typedef float v4 __attribute__((ext_vector_type(4)));
typedef float v2 __attribute__((ext_vector_type(2)));

// Full stable softplus [2 trans]
__device__ __forceinline__ float spf(float x) {
    float a = fabsf(x);
    float e = __expf(-a);
    float l = __logf(1.0f + e);
    return fmaxf(x, 0.0f) + l;
}
// Naive softplus [2 trans], safe for x in (-87, 88)
__device__ __forceinline__ float spn(float x) {
    return __logf(1.0f + __expf(x));
}
__device__ __forceinline__ float sigm(float x) {
    return 1.0f / (1.0f + __expf(-x));
}
__device__ __forceinline__ v4 splat(float s) { v4 r; r.x=s; r.y=s; r.z=s; r.w=s; return r; }
__device__ __forceinline__ v4 sp4(v4 x) {
    v4 r; r.x=spf(x.x); r.y=spf(x.y); r.z=spf(x.z); r.w=spf(x.w); return r;
}
__device__ __forceinline__ v4 sp4n(v4 x) {
    v4 r; r.x=spn(x.x); r.y=spn(x.y); r.z=spn(x.z); r.w=spn(x.w); return r;
}
// Quick softplus for z > 2: z + e^-z, |err| <= 0.0084 [1 trans]
__device__ __forceinline__ v4 spq4(v4 x) {
    v4 r;
    r.x = x.x + __expf(-x.x);
    r.y = x.y + __expf(-x.y);
    r.z = x.z + __expf(-x.z);
    r.w = x.w + __expf(-x.w);
    return r;
}
__device__ __forceinline__ v4 vfma(v4 a, float b, v4 c) {
    v2 bb; bb.x = b; bb.y = b;
    v4 r;
    r.lo = __builtin_elementwise_fma(a.lo, bb, c.lo);
    r.hi = __builtin_elementwise_fma(a.hi, bb, c.hi);
    return r;
}
__device__ __forceinline__ v4 vmin(v4 a, v4 b) {
    v4 r; r.x=fminf(a.x,b.x); r.y=fminf(a.y,b.y); r.z=fminf(a.z,b.z); r.w=fminf(a.w,b.w); return r;
}

// Setup: e_id, h_s, folded epilogue consts. H = h_s*I exactly (see R0 analysis).
__global__ void setup_kernel(const float* __restrict__ W0, const float* __restrict__ b0,
                             const float* __restrict__ Wh, const float* __restrict__ bh,
                             const float* __restrict__ Wf, const float* __restrict__ bf,
                             float* __restrict__ ws) {
    if (threadIdx.x != 0 || blockIdx.x != 0) return;
    float x[4] = {3.f, 1.f, -1.f, 3.f};
    float zin[5], h[5], zh[4][5];
    for (int j = 0; j < 5; ++j) {
        float z = b0[j];
        for (int m = 0; m < 4; ++m) z += x[m] * W0[m * 5 + j];
        zin[j] = z; h[j] = spf(z);
    }
    for (int i = 0; i < 4; ++i) {
        float hn[5];
        for (int j = 0; j < 5; ++j) {
            float z = bh[i * 5 + j];
            for (int k = 0; k < 5; ++k) z += h[k] * Wh[i * 25 + k * 5 + j];
            zh[i][j] = z; hn[j] = spf(z);
        }
        for (int j = 0; j < 5; ++j) h[j] = hn[j];
    }
    float zf = bf[0];
    for (int k = 0; k < 5; ++k) zf += h[k] * Wf[k];
    float e_id = spf(zf);
    float d[5];
    float szf = sigm(zf);
    for (int k = 0; k < 5; ++k) d[k] = Wf[k] * szf;
    for (int i = 3; i >= 0; --i) {
        float dz[5];
        for (int j = 0; j < 5; ++j) dz[j] = d[j] * sigm(zh[i][j]);
        for (int k = 0; k < 5; ++k) {
            float acc = 0.f;
            for (int j = 0; j < 5; ++j) acc += Wh[i * 25 + k * 5 + j] * dz[j];
            d[k] = acc;
        }
    }
    float dz0[5], g[4];
    for (int j = 0; j < 5; ++j) dz0[j] = d[j] * sigm(zin[j]);
    for (int m = 0; m < 4; ++m) {
        float acc = 0.f;
        for (int j = 0; j < 5; ++j) acc += W0[m * 5 + j] * dz0[j];
        g[m] = acc;
    }
    float h_s = -(2.f * g[0] + g[1] - g[2] + 4.f * g[3]);
    float c1 = 0.5f * h_s;
    ws[0] = e_id;
    ws[1] = h_s;
    ws[2] = c1;                    // res = e + c0 + c1*trC
    ws[3] = -e_id - 3.0f * c1;     // c0
}

__device__ __forceinline__ float scalar_sample(const float* f,
        const float* W0, const float* b0, const float* Wh, const float* bh,
        const float* Wf, const float* bf, float e_id, float h_s) {
    float f0=f[0],f1=f[1],f2=f[2],f3=f[3],f4=f[4],f5=f[5],f6=f[6],f7=f[7],f8=f[8];
    float c00=f0*f0+f3*f3+f6*f6, c11=f1*f1+f4*f4+f7*f7, c22=f2*f2+f5*f5+f8*f8;
    float c01=f0*f1+f3*f4+f6*f7, c02=f0*f2+f3*f5+f6*f8, c12=f1*f2+f4*f5+f7*f8;
    float trC=c00+c11+c22;
    float trC2=c00*c00+c11*c11+c22*c22+2.f*(c01*c01+c02*c02+c12*c12);
    float I2=0.5f*(trC*trC-trC2);
    float J=f0*(f4*f8-f5*f7)-f1*(f3*f8-f5*f6)+f2*(f3*f7-f4*f6);
    float h[5];
    for (int j=0;j<5;++j)
        h[j]=spf(b0[j]+trC*W0[j]+J*(W0[5+j]-W0[10+j])+I2*W0[15+j]);
    for (int l=0;l<4;++l){
        float hn[5];
        for (int j=0;j<5;++j){
            float z=bh[l*5+j];
            for (int k=0;k<5;++k) z=fmaf(h[k],Wh[l*25+k*5+j],z);
            hn[j]=spf(z);
        }
        for (int j=0;j<5;++j) h[j]=hn[j];
    }
    float zf=bf[0];
    for (int k=0;k<5;++k) zf=fmaf(h[k],Wf[k],zf);
    return (spf(zf)-e_id)+h_s*0.5f*(trC-3.0f);
}

// Invariants; I2 via principal 2x2 minors.
__device__ __forceinline__ void inv9(
        float f0, float f1, float f2, float f3, float f4,
        float f5, float f6, float f7, float f8,
        float& tc_o, float& J_o, float& I2_o) {
    float c00=f0*f0+f3*f3+f6*f6, c11=f1*f1+f4*f4+f7*f7, c22=f2*f2+f5*f5+f8*f8;
    float c01=f0*f1+f3*f4+f6*f7, c02=f0*f2+f3*f5+f6*f8, c12=f1*f2+f4*f5+f7*f8;
    tc_o = c00+c11+c22;
    float m0 = fmaf(c00, c11, -(c01*c01));
    float m1 = fmaf(c00, c22, -(c02*c02));
    float m2 = fmaf(c11, c22, -(c12*c12));
    I2_o = m0 + m1 + m2;
    float t0 = fmaf(f4, f8, -(f5*f7));
    float t1 = fmaf(f3, f8, -(f5*f6));
    float t2 = fmaf(f3, f7, -(f4*f6));
    J_o = fmaf(f2, t2, fmaf(-f1, t1, f0*t0));
}

// One-shot, 4 samples/thread. No min-wave cap (let VGPR float; spill-free).
// tail = c0 + c1*trC folded immediately after invariants so trC dies early.
__global__ __launch_bounds__(256) void main_kernel(
        const float* __restrict__ F,
        const float* __restrict__ W0, const float* __restrict__ b0,
        const float* __restrict__ Wh, const float* __restrict__ bh,
        const float* __restrict__ Wf, const float* __restrict__ bf,
        const float* __restrict__ cs,   // [e_id, h_s, c1, c0]
        float* __restrict__ out, int n) {
    const long long t = (long long)blockIdx.x * blockDim.x + threadIdx.x;
    const long long i0 = t * 4;
    if (i0 >= n) return;

    if (i0 + 4 <= (long long)n) {
        const v4* p = (const v4*)(F + i0 * 9);
        v4 a0=p[0],a1=p[1],a2=p[2],a3=p[3],a4=p[4],a5=p[5],a6=p[6],a7=p[7],a8=p[8];

        // transpose via named extracts (pure renames)
        float tc0,j0,q0, tc1,j1,q1, tc2,j2,q2, tc3,j3,q3;
        inv9(a0.x,a0.y,a0.z,a0.w, a1.x,a1.y,a1.z,a1.w, a2.x, tc0,j0,q0);
        inv9(a2.y,a2.z,a2.w, a3.x,a3.y,a3.z,a3.w, a4.x,a4.y, tc1,j1,q1);
        inv9(a4.z,a4.w, a5.x,a5.y,a5.z,a5.w, a6.x,a6.y,a6.z, tc2,j2,q2);
        inv9(a6.w, a7.x,a7.y,a7.z,a7.w, a8.x,a8.y,a8.z,a8.w, tc3,j3,q3);
        v4 trC, J, I2;
        trC.x=tc0; trC.y=tc1; trC.z=tc2; trC.w=tc3;
        J.x=j0; J.y=j1; J.z=j2; J.w=j3;
        I2.x=q0; I2.y=q1; I2.z=q2; I2.w=q3;

        // fold epilogue now: res = e + tail; trC no longer live after this
        const float c1 = cs[2], c0 = cs[3];
        v4 tail = vfma(trC, c1, splat(c0));

        // input layer (fold J and -J rows), vote: >3 -> spq (1 trans), else naive (2 trans)
        v4 h0,h1,h2,h3,h4;
        {
            v4 z0,z1,z2,z3,z4;
            #define L0Z(J_, Z_) \
                Z_ = splat(b0[J_]); \
                Z_ = vfma(trC, W0[J_], Z_); \
                Z_ = vfma(J, W0[5+J_]-W0[10+J_], Z_); \
                Z_ = vfma(I2, W0[15+J_], Z_);
            L0Z(0,z0) L0Z(1,z1) L0Z(2,z2) L0Z(3,z3) L0Z(4,z4)
            #undef L0Z
            v4 m = vmin(vmin(vmin(z0,z1),vmin(z2,z3)),z4);
            float mm = fminf(fminf(m.x,m.y),fminf(m.z,m.w));
            if (__all(mm > 3.0f)) {
                h0=spq4(z0); h1=spq4(z1); h2=spq4(z2); h3=spq4(z3); h4=spq4(z4);
            } else {
                h0=sp4n(z0); h1=sp4n(z1); h2=sp4n(z2); h3=sp4n(z3); h4=sp4n(z4);
            }
        }
        // hidden layers 1..4 with cascaded activation
        #pragma unroll
        for (int l = 0; l < 4; ++l) {
            v4 z0,z1,z2,z3,z4;
            #define ZJ(J_, Z_) \
                Z_ = splat(bh[l*5+J_]); \
                Z_ = vfma(h0, Wh[l*25+0*5+J_], Z_); \
                Z_ = vfma(h1, Wh[l*25+1*5+J_], Z_); \
                Z_ = vfma(h2, Wh[l*25+2*5+J_], Z_); \
                Z_ = vfma(h3, Wh[l*25+3*5+J_], Z_); \
                Z_ = vfma(h4, Wh[l*25+4*5+J_], Z_);
            ZJ(0,z0) ZJ(1,z1) ZJ(2,z2) ZJ(3,z3) ZJ(4,z4)
            #undef ZJ
            v4 m = vmin(vmin(vmin(z0,z1),vmin(z2,z3)),z4);
            float mm = fminf(fminf(m.x,m.y),fminf(m.z,m.w));
            if (__all(mm > 17.0f)) {
                h0=z0; h1=z1; h2=z2; h3=z3; h4=z4;          // identity, exact
            } else if (__all(mm > 2.0f)) {
                h0=spq4(z0); h1=spq4(z1); h2=spq4(z2); h3=spq4(z3); h4=spq4(z4);
            } else {
                h0=sp4(z0); h1=sp4(z1); h2=sp4(z2); h3=sp4(z3); h4=sp4(z4);
            }
        }
        v4 zf = splat(bf[0]);
        zf = vfma(h0, Wf[0], zf);
        zf = vfma(h1, Wf[1], zf);
        zf = vfma(h2, Wf[2], zf);
        zf = vfma(h3, Wf[3], zf);
        zf = vfma(h4, Wf[4], zf);
        float mf = fminf(fminf(zf.x, zf.y), fminf(zf.z, zf.w));
        v4 e;
        if (__all(mf > 17.0f)) e = zf;
        else if (__all(mf > 2.0f)) e = spq4(zf);
        else e = sp4(zf);

        *(v4*)(out + i0) = e + tail;
    } else {
        const float eid = cs[0], hs = cs[1];
        for (int s = 0; s < (int)(n - i0); ++s)
            out[i0 + s] = scalar_sample(F + (size_t)(i0 + s) * 9, W0, b0, Wh, bh, Wf, bf, eid, hs);
    }
}

extern "C" void kernel_launch(void* const* d_in, const int* in_sizes, int n_in,
                              void* d_out, int out_size, void* d_ws, size_t ws_size,
                              hipStream_t stream) {
    const float* F  = (const float*)d_in[0];
    const float* W0 = (const float*)d_in[1];
    const float* b0 = (const float*)d_in[2];
    const float* Wh = (const float*)d_in[3];
    const float* bh = (const float*)d_in[4];
    const float* Wf = (const float*)d_in[5];
    const float* bf = (const float*)d_in[6];
    float* out = (float*)d_out;
    float* ws  = (float*)d_ws;
    int n = in_sizes[0] / 9;
    setup_kernel<<<1, 64, 0, stream>>>(W0, b0, Wh, bh, Wf, bf, ws);
    int block = 256;
    long long threads = ((long long)n + 3) / 4;
    int grid = (int)((threads + block - 1) / block);
    if (grid < 1) grid = 1;
    main_kernel<<<grid, block, 0, stream>>>(F, W0, b0, Wh, bh, Wf, bf, ws, out, n);
}

// Round 16
// 48.710 us; speedup vs baseline: 1.1192x; 1.0613x over previous
//
#include <hip/hip_runtime.h>
#include <math.h>

typedef float v2 __attribute__((ext_vector_type(2)));

// Full stable softplus [2 trans]
__device__ __forceinline__ float spf(float x) {
    float a = fabsf(x);
    float e = __expf(-a);
    float l = __logf(1.0f + e);
    return fmaxf(x, 0.0f) + l;
}
// Naive softplus [2 trans], safe for x in (-87, 88)
__device__ __forceinline__ float spn(float x) {
    return __logf(1.0f + __expf(x));
}
__device__ __forceinline__ float sigm(float x) {
    return 1.0f / (1.0f + __expf(-x));
}
__device__ __forceinline__ v2 splat2(float s) { v2 r; r.x=s; r.y=s; return r; }
__device__ __forceinline__ v2 sp2(v2 x)  { v2 r; r.x=spf(x.x); r.y=spf(x.y); return r; }
__device__ __forceinline__ v2 sp2n(v2 x) { v2 r; r.x=spn(x.x); r.y=spn(x.y); return r; }
// Quick softplus for z > 2: z + e^-z, |err| <= 0.0084 [1 trans]
__device__ __forceinline__ v2 spq2(v2 x) {
    v2 r;
    r.x = x.x + __expf(-x.x);
    r.y = x.y + __expf(-x.y);
    return r;
}
__device__ __forceinline__ v2 vfma2(v2 a, float b, v2 c) {
    v2 bb; bb.x = b; bb.y = b;
    return __builtin_elementwise_fma(a, bb, c);
}
__device__ __forceinline__ v2 vmin2(v2 a, v2 b) {
    v2 r; r.x=fminf(a.x,b.x); r.y=fminf(a.y,b.y); return r;
}

// Setup: e_id, h_s, folded epilogue consts. H = h_s*I exactly (see R0 analysis).
__global__ void setup_kernel(const float* __restrict__ W0, const float* __restrict__ b0,
                             const float* __restrict__ Wh, const float* __restrict__ bh,
                             const float* __restrict__ Wf, const float* __restrict__ bf,
                             float* __restrict__ ws) {
    if (threadIdx.x != 0 || blockIdx.x != 0) return;
    float x[4] = {3.f, 1.f, -1.f, 3.f};
    float zin[5], h[5], zh[4][5];
    for (int j = 0; j < 5; ++j) {
        float z = b0[j];
        for (int m = 0; m < 4; ++m) z += x[m] * W0[m * 5 + j];
        zin[j] = z; h[j] = spf(z);
    }
    for (int i = 0; i < 4; ++i) {
        float hn[5];
        for (int j = 0; j < 5; ++j) {
            float z = bh[i * 5 + j];
            for (int k = 0; k < 5; ++k) z += h[k] * Wh[i * 25 + k * 5 + j];
            zh[i][j] = z; hn[j] = spf(z);
        }
        for (int j = 0; j < 5; ++j) h[j] = hn[j];
    }
    float zf = bf[0];
    for (int k = 0; k < 5; ++k) zf += h[k] * Wf[k];
    float e_id = spf(zf);
    float d[5];
    float szf = sigm(zf);
    for (int k = 0; k < 5; ++k) d[k] = Wf[k] * szf;
    for (int i = 3; i >= 0; --i) {
        float dz[5];
        for (int j = 0; j < 5; ++j) dz[j] = d[j] * sigm(zh[i][j]);
        for (int k = 0; k < 5; ++k) {
            float acc = 0.f;
            for (int j = 0; j < 5; ++j) acc += Wh[i * 25 + k * 5 + j] * dz[j];
            d[k] = acc;
        }
    }
    float dz0[5], g[4];
    for (int j = 0; j < 5; ++j) dz0[j] = d[j] * sigm(zin[j]);
    for (int m = 0; m < 4; ++m) {
        float acc = 0.f;
        for (int j = 0; j < 5; ++j) acc += W0[m * 5 + j] * dz0[j];
        g[m] = acc;
    }
    float h_s = -(2.f * g[0] + g[1] - g[2] + 4.f * g[3]);
    float c1 = 0.5f * h_s;
    ws[0] = e_id;
    ws[1] = h_s;
    ws[2] = c1;                    // res = e + c0 + c1*trC
    ws[3] = -e_id - 3.0f * c1;     // c0
}

__device__ __forceinline__ float scalar_sample(const float* f,
        const float* W0, const float* b0, const float* Wh, const float* bh,
        const float* Wf, const float* bf, float e_id, float h_s) {
    float f0=f[0],f1=f[1],f2=f[2],f3=f[3],f4=f[4],f5=f[5],f6=f[6],f7=f[7],f8=f[8];
    float c00=f0*f0+f3*f3+f6*f6, c11=f1*f1+f4*f4+f7*f7, c22=f2*f2+f5*f5+f8*f8;
    float c01=f0*f1+f3*f4+f6*f7, c02=f0*f2+f3*f5+f6*f8, c12=f1*f2+f4*f5+f7*f8;
    float trC=c00+c11+c22;
    float trC2=c00*c00+c11*c11+c22*c22+2.f*(c01*c01+c02*c02+c12*c12);
    float I2=0.5f*(trC*trC-trC2);
    float J=f0*(f4*f8-f5*f7)-f1*(f3*f8-f5*f6)+f2*(f3*f7-f4*f6);
    float h[5];
    for (int j=0;j<5;++j)
        h[j]=spf(b0[j]+trC*W0[j]+J*(W0[5+j]-W0[10+j])+I2*W0[15+j]);
    for (int l=0;l<4;++l){
        float hn[5];
        for (int j=0;j<5;++j){
            float z=bh[l*5+j];
            for (int k=0;k<5;++k) z=fmaf(h[k],Wh[l*25+k*5+j],z);
            hn[j]=spf(z);
        }
        for (int j=0;j<5;++j) h[j]=hn[j];
    }
    float zf=bf[0];
    for (int k=0;k<5;++k) zf=fmaf(h[k],Wf[k],zf);
    return (spf(zf)-e_id)+h_s*0.5f*(trC-3.0f);
}

// Invariants; I2 via principal 2x2 minors.
__device__ __forceinline__ void inv9(
        float f0, float f1, float f2, float f3, float f4,
        float f5, float f6, float f7, float f8,
        float& tc_o, float& J_o, float& I2_o) {
    float c00=f0*f0+f3*f3+f6*f6, c11=f1*f1+f4*f4+f7*f7, c22=f2*f2+f5*f5+f8*f8;
    float c01=f0*f1+f3*f4+f6*f7, c02=f0*f2+f3*f5+f6*f8, c12=f1*f2+f4*f5+f7*f8;
    tc_o = c00+c11+c22;
    float m0 = fmaf(c00, c11, -(c01*c01));
    float m1 = fmaf(c00, c22, -(c02*c02));
    float m2 = fmaf(c11, c22, -(c12*c12));
    I2_o = m0 + m1 + m2;
    float t0 = fmaf(f4, f8, -(f5*f7));
    float t1 = fmaf(f3, f8, -(f5*f6));
    float t2 = fmaf(f3, f7, -(f4*f6));
    J_o = fmaf(f2, t2, fmaf(-f1, t1, f0*t0));
}

// 2 samples/thread: half the per-thread body of the 4/thread base, 2x waves
// (32768), VGPR ~55 -> true 8 waves/SIMD. Loads: 9 x dwordx2 (72B/thread is
// 8-aligned). Same cascaded-softplus structure as the 51.7us base.
__global__ __launch_bounds__(256, 8) void main_kernel(
        const float* __restrict__ F,
        const float* __restrict__ W0, const float* __restrict__ b0,
        const float* __restrict__ Wh, const float* __restrict__ bh,
        const float* __restrict__ Wf, const float* __restrict__ bf,
        const float* __restrict__ cs,   // [e_id, h_s, c1, c0]
        float* __restrict__ out, int n) {
    const long long t = (long long)blockIdx.x * blockDim.x + threadIdx.x;
    const long long i0 = t * 2;
    if (i0 >= n) return;

    if (i0 + 2 <= (long long)n) {
        const v2* p = (const v2*)(F + i0 * 9);   // 8B-aligned
        v2 e0=p[0],e1=p[1],e2=p[2],e3=p[3],e4=p[4],e5=p[5],e6=p[6],e7=p[7],e8=p[8];

        float tcA,jA,qA, tcB,jB,qB;
        inv9(e0.x,e0.y,e1.x,e1.y,e2.x,e2.y,e3.x,e3.y,e4.x, tcA,jA,qA);
        inv9(e4.y,e5.x,e5.y,e6.x,e6.y,e7.x,e7.y,e8.x,e8.y, tcB,jB,qB);
        v2 trC, J, I2;
        trC.x=tcA; trC.y=tcB;
        J.x=jA;   J.y=jB;
        I2.x=qA;  I2.y=qB;

        // fold epilogue now: res = e + tail; trC dies here
        const float c1 = cs[2], c0 = cs[3];
        v2 tail = vfma2(trC, c1, splat2(c0));

        // input layer (fold J and -J rows), vote: >3 -> spq (1 trans), else naive
        v2 h0,h1,h2,h3,h4;
        {
            v2 z0,z1,z2,z3,z4;
            #define L0Z(J_, Z_) \
                Z_ = splat2(b0[J_]); \
                Z_ = vfma2(trC, W0[J_], Z_); \
                Z_ = vfma2(J, W0[5+J_]-W0[10+J_], Z_); \
                Z_ = vfma2(I2, W0[15+J_], Z_);
            L0Z(0,z0) L0Z(1,z1) L0Z(2,z2) L0Z(3,z3) L0Z(4,z4)
            #undef L0Z
            v2 m = vmin2(vmin2(vmin2(z0,z1),vmin2(z2,z3)),z4);
            float mm = fminf(m.x,m.y);
            if (__all(mm > 3.0f)) {
                h0=spq2(z0); h1=spq2(z1); h2=spq2(z2); h3=spq2(z3); h4=spq2(z4);
            } else {
                h0=sp2n(z0); h1=sp2n(z1); h2=sp2n(z2); h3=sp2n(z3); h4=sp2n(z4);
            }
        }
        // hidden layers 1..4 with cascaded activation
        #pragma unroll
        for (int l = 0; l < 4; ++l) {
            v2 z0,z1,z2,z3,z4;
            #define ZJ(J_, Z_) \
                Z_ = splat2(bh[l*5+J_]); \
                Z_ = vfma2(h0, Wh[l*25+0*5+J_], Z_); \
                Z_ = vfma2(h1, Wh[l*25+1*5+J_], Z_); \
                Z_ = vfma2(h2, Wh[l*25+2*5+J_], Z_); \
                Z_ = vfma2(h3, Wh[l*25+3*5+J_], Z_); \
                Z_ = vfma2(h4, Wh[l*25+4*5+J_], Z_);
            ZJ(0,z0) ZJ(1,z1) ZJ(2,z2) ZJ(3,z3) ZJ(4,z4)
            #undef ZJ
            v2 m = vmin2(vmin2(vmin2(z0,z1),vmin2(z2,z3)),z4);
            float mm = fminf(m.x,m.y);
            if (__all(mm > 17.0f)) {
                h0=z0; h1=z1; h2=z2; h3=z3; h4=z4;          // identity, exact
            } else if (__all(mm > 2.0f)) {
                h0=spq2(z0); h1=spq2(z1); h2=spq2(z2); h3=spq2(z3); h4=spq2(z4);
            } else {
                h0=sp2(z0); h1=sp2(z1); h2=sp2(z2); h3=sp2(z3); h4=sp2(z4);
            }
        }
        v2 zf = splat2(bf[0]);
        zf = vfma2(h0, Wf[0], zf);
        zf = vfma2(h1, Wf[1], zf);
        zf = vfma2(h2, Wf[2], zf);
        zf = vfma2(h3, Wf[3], zf);
        zf = vfma2(h4, Wf[4], zf);
        float mf = fminf(zf.x, zf.y);
        v2 e;
        if (__all(mf > 17.0f)) e = zf;
        else if (__all(mf > 2.0f)) e = spq2(zf);
        else e = sp2(zf);

        *(v2*)(out + i0) = e + tail;
    } else {
        const float eid = cs[0], hs = cs[1];
        out[i0] = scalar_sample(F + (size_t)i0 * 9, W0, b0, Wh, bh, Wf, bf, eid, hs);
    }
}

extern "C" void kernel_launch(void* const* d_in, const int* in_sizes, int n_in,
                              void* d_out, int out_size, void* d_ws, size_t ws_size,
                              hipStream_t stream) {
    const float* F  = (const float*)d_in[0];
    const float* W0 = (const float*)d_in[1];
    const float* b0 = (const float*)d_in[2];
    const float* Wh = (const float*)d_in[3];
    const float* bh = (const float*)d_in[4];
    const float* Wf = (const float*)d_in[5];
    const float* bf = (const float*)d_in[6];
    float* out = (float*)d_out;
    float* ws  = (float*)d_ws;
    int n = in_sizes[0] / 9;
    setup_kernel<<<1, 64, 0, stream>>>(W0, b0, Wh, bh, Wf, bf, ws);
    int block = 256;
    long long threads = ((long long)n + 1) / 2;
    int grid = (int)((threads + block - 1) / block);
    if (grid < 1) grid = 1;
    main_kernel<<<grid, block, 0, stream>>>(F, W0, b0, Wh, bh, Wf, bf, ws, out, n);
}